// Round 9
// baseline (334.491 us; speedup 1.0000x reference)
//
#include <hip/hip_runtime.h>
#include <hip/hip_bf16.h>
#include <hip/hip_cooperative_groups.h>
#include <stdint.h>

namespace cg = cooperative_groups;

// Problem constants: B=32, T=512, C=F=384, M=2048.
#define B_ 32
#define T_ 512
#define C_ 384
#define F_ 384
#define M_ 2048
#define PT (T_ + 2)      // padded time rows per batch (halo for K=3 conv)
#define KTOT (3 * C_)    // GEMM K = 1152

typedef __bf16 bf16x8 __attribute__((ext_vector_type(8)));
typedef float  f32x4  __attribute__((ext_vector_type(4)));
typedef unsigned short ushort_t;

__device__ __forceinline__ ushort_t f2bf(float f) {
  __hip_bfloat16 h = __float2bfloat16(f);
  return *reinterpret_cast<ushort_t*>(&h);
}
__device__ __forceinline__ uint32_t pack2(float a, float b) {
  return (uint32_t)f2bf(a) | ((uint32_t)f2bf(b) << 16);
}
__device__ __forceinline__ void gload16(const void* g, void* l) {
  __builtin_amdgcn_global_load_lds(
      (const __attribute__((address_space(1))) uint32_t*)g,
      (__attribute__((address_space(3))) uint32_t*)l, 16, 0, 0);
}

struct Params {
  const float* enc; const float* mask; const int* target;
  const float* w1; const float* b1; const float* g1; const float* be1;
  const float* w2; const float* b2; const float* g2; const float* be2;
  const float* wl; const float* bl;
  ushort_t* x1p; ushort_t* wt1; ushort_t* wt2; int* cs;
  float* out0; float* dec; float* dpo;
};

// ---------------------------------------------------------------------------
// Conv-GEMM + bias + ReLU + LN (+ linear for LAST). X already staged in ldsX
// ([66 rows][384 cols] bf16, chunk-XOR swizzled). K-loop double-buffers W only.
// 8 waves, wave owns 48n x 64m; one barrier per K-step (R5-proven loop).
template <bool LAST>
__device__ __forceinline__ void gemm_core(
    char* ldsW0, char* ldsW1, const char* ldsX,
    float (*red)[64][2], float (*stats)[2],
    const ushort_t* __restrict__ wt, const float* __restrict__ bias,
    const float* __restrict__ g, const float* __restrict__ be,
    const float* __restrict__ wl, const float* __restrict__ bl,
    const float* __restrict__ mask,
    ushort_t* __restrict__ xout, float* __restrict__ dpo,
    int b, int t0, int tid, int l, int q, int r16, int wid) {
  f32x4 acc[3][4];
#pragma unroll
  for (int fn = 0; fn < 3; ++fn)
#pragma unroll
    for (int fm = 0; fm < 4; ++fm) acc[fn][fm] = (f32x4){0.f, 0.f, 0.f, 0.f};

  // Stage W K-step s (48 KB = 6 passes x 8 KB), 16B/lane, linear LDS dest,
  // chunk-XOR swizzle via pre-swizzled global source (rule 21).
  auto STAGE_W = [&](int buf, int s) {
    const int kk = s / 6, c0 = (s % 6) * 64;
    char* dst = buf ? ldsW1 : ldsW0;
#pragma unroll
    for (int i = 0; i < 6; ++i) {
      int lin = i * 8192 + tid * 16;
      int row = lin >> 7, ch = ((lin >> 4) & 7) ^ (row & 7);
      gload16(wt + (size_t)row * KTOT + kk * C_ + c0 + ch * 8,
              dst + i * 8192 + (wid << 10));
    }
  };

  STAGE_W(0, 0);
  __syncthreads();  // drains vmcnt (W) + lgkm (X ds_writes): everything ready

  int cur = 0;
  for (int s = 0; s < 18; ++s) {
    if (s < 17) STAGE_W(cur ^ 1, s + 1);  // prefetch flies under compute
    const char* W = cur ? ldsW1 : ldsW0;
    const int kk = s / 6, c128 = (s % 6) * 128;
#pragma unroll
    for (int ks = 0; ks < 2; ++ks) {
      bf16x8 af[3], bx[4];
#pragma unroll
      for (int fn = 0; fn < 3; ++fn) {
        int rr = wid * 48 + fn * 16 + r16;
        af[fn] = *(const bf16x8*)(W + rr * 128 + ((((ks * 4 + q)) ^ (rr & 7)) << 4));
      }
#pragma unroll
      for (int fm = 0; fm < 4; ++fm) {
        int rl = fm * 16 + r16 + kk;
        bx[fm] = *(const bf16x8*)(ldsX + rl * 768 + c128 +
                                  (((ks * 4 + q) ^ (rl & 7)) << 4));
      }
#pragma unroll
      for (int fn = 0; fn < 3; ++fn)
#pragma unroll
        for (int fm = 0; fm < 4; ++fm)
          acc[fn][fm] = __builtin_amdgcn_mfma_f32_16x16x32_bf16(
              af[fn], bx[fm], acc[fn][fm], 0, 0, 0);
    }
    __syncthreads();  // stage(s+1) done + reads(s) done
    cur ^= 1;
  }

  // bias + ReLU
#pragma unroll
  for (int fn = 0; fn < 3; ++fn) {
    const int nb = wid * 48 + fn * 16 + q * 4;
    float b0 = bias[nb], b1 = bias[nb + 1], b2 = bias[nb + 2], b3 = bias[nb + 3];
#pragma unroll
    for (int fm = 0; fm < 4; ++fm) {
      acc[fn][fm][0] = fmaxf(acc[fn][fm][0] + b0, 0.f);
      acc[fn][fm][1] = fmaxf(acc[fn][fm][1] + b1, 0.f);
      acc[fn][fm][2] = fmaxf(acc[fn][fm][2] + b2, 0.f);
      acc[fn][fm][3] = fmaxf(acc[fn][fm][3] + b3, 0.f);
    }
  }

  // LN stats
#pragma unroll
  for (int fm = 0; fm < 4; ++fm) {
    float s = 0.f, s2 = 0.f;
#pragma unroll
    for (int fn = 0; fn < 3; ++fn)
#pragma unroll
      for (int j = 0; j < 4; ++j) {
        float v = acc[fn][fm][j];
        s += v; s2 += v * v;
      }
    s += __shfl_xor(s, 16); s += __shfl_xor(s, 32);
    s2 += __shfl_xor(s2, 16); s2 += __shfl_xor(s2, 32);
    if (l < 16) { red[wid][fm * 16 + r16][0] = s; red[wid][fm * 16 + r16][1] = s2; }
  }
  __syncthreads();
  if (tid < 64) {
    float S = 0.f, S2 = 0.f;
#pragma unroll
    for (int w = 0; w < 8; ++w) { S += red[w][tid][0]; S2 += red[w][tid][1]; }
    float mu = S / F_;
    stats[tid][0] = mu;
    stats[tid][1] = rsqrtf(S2 / F_ - mu * mu + 1e-5f);
  }
  __syncthreads();

  if (!LAST) {
#pragma unroll
    for (int fn = 0; fn < 3; ++fn) {
      const int nb = wid * 48 + fn * 16 + q * 4;
      float g0 = g[nb], g1 = g[nb + 1], g2 = g[nb + 2], g3 = g[nb + 3];
      float e0 = be[nb], e1 = be[nb + 1], e2 = be[nb + 2], e3 = be[nb + 3];
#pragma unroll
      for (int fm = 0; fm < 4; ++fm) {
        const int m = fm * 16 + r16;
        const float mu = stats[m][0], rs = stats[m][1];
        uint32_t p0 = pack2((acc[fn][fm][0] - mu) * rs * g0 + e0,
                            (acc[fn][fm][1] - mu) * rs * g1 + e1);
        uint32_t p1 = pack2((acc[fn][fm][2] - mu) * rs * g2 + e2,
                            (acc[fn][fm][3] - mu) * rs * g3 + e3);
        *(uint2*)(xout + ((size_t)(b * PT + 1 + t0 + m)) * C_ + nb) =
            make_uint2(p0, p1);
      }
    }
  } else {
    float p[4] = {0.f, 0.f, 0.f, 0.f};
#pragma unroll
    for (int fn = 0; fn < 3; ++fn) {
      const int nb = wid * 48 + fn * 16 + q * 4;
      float g0 = g[nb], g1 = g[nb + 1], g2 = g[nb + 2], g3 = g[nb + 3];
      float e0 = be[nb], e1 = be[nb + 1], e2 = be[nb + 2], e3 = be[nb + 3];
      float l0 = wl[nb], l1 = wl[nb + 1], l2 = wl[nb + 2], l3 = wl[nb + 3];
#pragma unroll
      for (int fm = 0; fm < 4; ++fm) {
        const int m = fm * 16 + r16;
        const float mu = stats[m][0], rs = stats[m][1];
        p[fm] += ((acc[fn][fm][0] - mu) * rs * g0 + e0) * l0 +
                 ((acc[fn][fm][1] - mu) * rs * g1 + e1) * l1 +
                 ((acc[fn][fm][2] - mu) * rs * g2 + e2) * l2 +
                 ((acc[fn][fm][3] - mu) * rs * g3 + e3) * l3;
      }
    }
    __syncthreads();  // red reuse
#pragma unroll
    for (int fm = 0; fm < 4; ++fm) {
      float s = p[fm];
      s += __shfl_xor(s, 16); s += __shfl_xor(s, 32);
      if (l < 16) red[wid][fm * 16 + r16][0] = s;
    }
    __syncthreads();
    if (tid < 64) {
      float S = 0.f;
#pragma unroll
      for (int w = 0; w < 8; ++w) S += red[w][tid][0];
      int t = t0 + tid;
      dpo[b * T_ + t] = (S + bl[0]) * mask[b * T_ + t];
    }
  }
}

// ---------------------------------------------------------------------------
// Single cooperative megakernel: prep | gemm1 | gemm2 | expand, grid.sync()
// between phases. 256 blocks x 512 threads = 1 block/CU, 2 waves/SIMD.
__global__ __launch_bounds__(512, 1) void mega_kernel(Params p) {
  __shared__ char ldsW0[F_ * 128];     // 48 KB W buffer A
  __shared__ char ldsW1[F_ * 128];     // 48 KB W buffer B
  __shared__ char ldsX[66 * 768];      // 50.7 KB X rows t0-1..t0+64, swizzled
  __shared__ float red[8][64][2];
  __shared__ float stats[64][2];

  const int tid = threadIdx.x;
  const int l = tid & 63, q = l >> 4, r16 = l & 15;
  const int wid = tid >> 6;            // 0..7
  const int bid = blockIdx.x;
  const int b = bid >> 3, t0 = (bid & 7) * 64;
  cg::grid_group grid = cg::this_grid();

  // ---------------- phase 0: prep (grid-stride) ----------------
  {
    const int gtid = bid * 512 + tid;  // 0..131071
    // weight transposes: wtX[n][kk*C+c] = bf16(wX[n][c][kk])
    for (int idx = gtid; idx < 2 * F_ * KTOT; idx += 256 * 512) {
      int w = idx >= F_ * KTOT;
      int o = idx - (w ? F_ * KTOT : 0);
      int n = o / KTOT, rem = o - n * KTOT, kk = rem / C_, c = rem - kk * C_;
      const float* src = w ? p.w2 : p.w1;
      ushort_t* dst = w ? p.wt2 : p.wt1;
      dst[o] = f2bf(src[(n * C_ + c) * 3 + kk]);
    }
    // x1p halo rows (pr==0 and pr==T+1) zero
    if (gtid < B_ * C_) {
      int bb = gtid / C_, c = gtid - bb * C_;
      p.x1p[(size_t)(bb * PT) * C_ + c] = 0;
      p.x1p[(size_t)(bb * PT + T_ + 1) * C_ + c] = 0;
    }
    // cumsum: one wave per batch row on blocks 0..31
    if (bid < B_ && tid < 64) {
      int base = bid * T_ + l * 8;
      int v[8];
#pragma unroll
      for (int i = 0; i < 8; ++i) v[i] = p.target[base + i];
#pragma unroll
      for (int i = 1; i < 8; ++i) v[i] += v[i - 1];
      int tot = v[7];
      int inc = tot;
#pragma unroll
      for (int d = 1; d < 64; d <<= 1) {
        int t = __shfl_up(inc, d);
        if (l >= d) inc += t;
      }
      int excl = inc - tot;
#pragma unroll
      for (int i = 0; i < 8; ++i) p.cs[base + i] = v[i] + excl;
    }
  }
  __threadfence();
  grid.sync();

  // ---------------- phase 1: gemm1 (X from enc f32 + mask) ----------------
#pragma unroll
  for (int ps = 0; ps < 7; ++ps) {
    int idx = ps * 512 + tid;          // 16B-chunk index, 66*48 total
    if (idx < 66 * 48) {
      int rl = idx / 48, cp = idx - rl * 48;
      int gc = cp >> 3, ch = cp & 7;
      int t = t0 - 1 + rl;
      uint4 o = make_uint4(0, 0, 0, 0);
      if (t >= 0 && t < T_) {
        const float* src = p.enc + ((size_t)b * T_ + t) * C_ + gc * 64 + ch * 8;
        float4 u = *(const float4*)src;
        float4 v = *(const float4*)(src + 4);
        float m = p.mask[b * T_ + t];
        o = make_uint4(pack2(u.x * m, u.y * m), pack2(u.z * m, u.w * m),
                       pack2(v.x * m, v.y * m), pack2(v.z * m, v.w * m));
      }
      *(uint4*)(ldsX + rl * 768 + gc * 128 + ((ch ^ (rl & 7)) << 4)) = o;
    }
  }
  gemm_core<false>(ldsW0, ldsW1, ldsX, red, stats, p.wt1, p.b1, p.g1, p.be1,
                   nullptr, nullptr, nullptr, p.x1p, nullptr,
                   b, t0, tid, l, q, r16, wid);
  __threadfence();
  grid.sync();

  // ---------------- phase 2: gemm2 (X from x1p bf16) ----------------
#pragma unroll
  for (int ps = 0; ps < 7; ++ps) {
    int idx = ps * 512 + tid;
    if (idx < 66 * 48) {
      int rl = idx / 48, cp = idx - rl * 48;
      int gc = cp >> 3, ch = cp & 7;
      uint4 v = *(const uint4*)(p.x1p + ((size_t)(b * PT + t0 + rl)) * C_ +
                                gc * 64 + ch * 8);
      *(uint4*)(ldsX + rl * 768 + gc * 128 + ((ch ^ (rl & 7)) << 4)) = v;
    }
  }
  gemm_core<true>(ldsW0, ldsW1, ldsX, red, stats, p.wt2, p.b2, p.g2, p.be2,
                  p.wl, p.bl, p.mask, nullptr, p.dpo,
                  b, t0, tid, l, q, r16, wid);
  __threadfence();
  grid.sync();

  // ---------------- phase 3: expand ----------------
  {
    int* scs = (int*)ldsX;             // reuse X LDS for the cumsum table
    for (int i = tid; i < T_; i += 512) scs[i] = p.cs[b * T_ + i];
    __syncthreads();
    const int total = scs[T_ - 1];
    const int p0 = (bid & 7) * 256;
    const float4 zero = make_float4(0.f, 0.f, 0.f, 0.f);
#pragma unroll 1
    for (int it = 0; it < 32; ++it) {
      const int pos = p0 + it * 8 + wid;
      const bool valid = pos < total;
      int idx = 0;
#pragma unroll
      for (int step = 512; step; step >>= 1)
        if (idx + step <= T_ && scs[idx + step - 1] <= pos) idx += step;
      int src = idx < T_ ? idx : T_ - 1;
      const float4* srow = (const float4*)(p.enc + ((size_t)b * T_ + src) * C_);
      float4* orow = (float4*)(p.out0 + ((size_t)b * M_ + pos) * C_);
      orow[l] = valid ? srow[l] : zero;
      if (l < 32) orow[64 + l] = valid ? srow[64 + l] : zero;
      if (l == 0) p.dec[b * M_ + pos] = valid ? (float)(pos + 1) : 0.f;
    }
  }
}

// ---------------------------------------------------------------------------
extern "C" void kernel_launch(void* const* d_in, const int* in_sizes, int n_in,
                              void* d_out, int out_size, void* d_ws,
                              size_t ws_size, hipStream_t stream) {
  Params P;
  P.enc    = (const float*)d_in[0];
  P.mask   = (const float*)d_in[1];
  P.target = (const int*)d_in[2];
  P.w1  = (const float*)d_in[4];
  P.b1  = (const float*)d_in[5];
  P.g1  = (const float*)d_in[6];
  P.be1 = (const float*)d_in[7];
  P.w2  = (const float*)d_in[8];
  P.b2  = (const float*)d_in[9];
  P.g2  = (const float*)d_in[10];
  P.be2 = (const float*)d_in[11];
  P.wl  = (const float*)d_in[12];
  P.bl  = (const float*)d_in[13];

  // Workspace (bf16): x1p (padded) | wt1 | wt2 | cs (i32). xm is GONE.
  ushort_t* x1p = (ushort_t*)d_ws;                    // [B][PT][C]
  P.x1p = x1p;
  P.wt1 = x1p + (size_t)B_ * PT * C_;                 // [F][KTOT]
  P.wt2 = P.wt1 + (size_t)F_ * KTOT;
  P.cs  = (int*)(P.wt2 + (size_t)F_ * KTOT);          // [B][T]

  P.out0 = (float*)d_out;                             // [B,M,C]
  P.dec  = P.out0 + (size_t)B_ * M_ * C_;             // [B,M]
  P.dpo  = P.dec + (size_t)B_ * M_;                   // [B,T]

  void* args[] = {(void*)&P};
  hipLaunchCooperativeKernel((const void*)mega_kernel, dim3(256), dim3(512),
                             args, 0, stream);
}

// Round 10
// 99.191 us; speedup vs baseline: 3.3722x; 3.3722x over previous
//
#include <hip/hip_runtime.h>
#include <hip/hip_bf16.h>
#include <stdint.h>

// Problem constants: B=32, T=512, C=F=384, M=2048.
#define B_ 32
#define T_ 512
#define C_ 384
#define F_ 384
#define M_ 2048
#define PT (T_ + 2)      // padded time rows per batch (halo for K=3 conv)
#define KTOT (3 * C_)    // GEMM K = 1152

typedef __bf16 bf16x8 __attribute__((ext_vector_type(8)));
typedef float  f32x4  __attribute__((ext_vector_type(4)));
typedef unsigned short ushort_t;

__device__ __forceinline__ ushort_t f2bf(float f) {
  __hip_bfloat16 h = __float2bfloat16(f);
  return *reinterpret_cast<ushort_t*>(&h);
}
__device__ __forceinline__ uint32_t pack2(float a, float b) {
  return (uint32_t)f2bf(a) | ((uint32_t)f2bf(b) << 16);
}
__device__ __forceinline__ void gload16(const void* g, void* l) {
  __builtin_amdgcn_global_load_lds(
      (const __attribute__((address_space(1))) uint32_t*)g,
      (__attribute__((address_space(3))) uint32_t*)l, 16, 0, 0);
}

// ---------------------------------------------------------------------------
// prep: weight transposes | x1p halo zeros | cumsum.  (xm is GONE.)
#define NWB 3456   // = 2*F*KTOT/256
__global__ __launch_bounds__(256) void prep_kernel(
    const int* __restrict__ target,
    const float* __restrict__ w1, const float* __restrict__ w2,
    ushort_t* __restrict__ x1p,
    ushort_t* __restrict__ wt1, ushort_t* __restrict__ wt2,
    int* __restrict__ cs) {
  const int gid = blockIdx.x;
  const int tid = threadIdx.x;
  if (gid < NWB) {
    int idx = gid * 256 + tid;          // 0 .. 2*F*KTOT
    int w = idx >= F_ * KTOT;
    int o = idx - (w ? F_ * KTOT : 0);
    int n = o / KTOT, rem = o - n * KTOT, kk = rem / C_, c = rem - kk * C_;
    const float* src = w ? w2 : w1;
    ushort_t* dst = w ? wt2 : wt1;
    dst[o] = f2bf(src[(n * C_ + c) * 3 + kk]);
  } else if (gid < NWB + 48) {
    int idx = (gid - NWB) * 256 + tid;  // 0 .. B*C
    int bb = idx / C_, c = idx - bb * C_;
    x1p[(size_t)(bb * PT) * C_ + c] = 0;
    x1p[(size_t)(bb * PT + T_ + 1) * C_ + c] = 0;
  } else {
    int b = (gid - NWB - 48) * 4 + (tid >> 6);
    int lane = tid & 63;
    int base = b * T_ + lane * 8;
    int v[8];
#pragma unroll
    for (int i = 0; i < 8; ++i) v[i] = target[base + i];
#pragma unroll
    for (int i = 1; i < 8; ++i) v[i] += v[i - 1];
    int tot = v[7];
    int inc = tot;
#pragma unroll
    for (int d = 1; d < 64; d <<= 1) {
      int t = __shfl_up(inc, d);
      if (lane >= d) inc += t;
    }
    int excl = inc - tot;
#pragma unroll
    for (int i = 0; i < 8; ++i) cs[base + i] = v[i] + excl;
  }
}

// ---------------------------------------------------------------------------
// Conv-GEMM + bias + ReLU + LN (+ final linear for LAST).
// X ([66 rows][384] bf16, chunk-XOR swizzled) staged ONCE per block
//   (LAST=false: from enc f32 * mask; LAST=true: from x1p bf16).
// K-loop stages W only (48 KB/step, double-buffered) with a COUNTED-vmcnt
// pipeline: issue next stage's 6 gloads, s_waitcnt vmcnt(6) (old stage done,
// new stays in flight ACROSS the barrier), raw s_barrier, compute, raw
// s_barrier. Never drains to 0 mid-loop (T4-minimum).
// 8 waves, wave owns 48n x 64m. Grid = 256 = 1 block/CU, 2 waves/SIMD.
template <bool LAST>
__global__ __launch_bounds__(512, 1) void gemm_ln_kernel(
    const float* __restrict__ enc,     // [B,T,C] f32      (LAST=false)
    const float* __restrict__ mask,    // [B*T]
    const ushort_t* __restrict__ x1p,  // [B][PT][C] bf16  (LAST=true in)
    const ushort_t* __restrict__ wt,   // [F][KTOT] bf16
    const float* __restrict__ bias, const float* __restrict__ g,
    const float* __restrict__ be,
    const float* __restrict__ wl, const float* __restrict__ bl,
    ushort_t* __restrict__ xout,       // [B][PT][C] (LAST=false out)
    float* __restrict__ dpo) {         // [B*T]      (LAST=true out)
  __shared__ char ldsW[2][48 * 1024];  // 96 KB W double buffer
  __shared__ char ldsX[66 * 768];      // 49.5 KB X, swizzled
  __shared__ float red[8][64][2];
  __shared__ float stats[64][2];

  const int tid = threadIdx.x;
  const int l = tid & 63, q = l >> 4, r16 = l & 15;
  const int wid = tid >> 6;            // 0..7
  const int b = blockIdx.x >> 3, t0 = (blockIdx.x & 7) * 64;

  // ---- stage X once (reg path, swizzled ds_write; R9-validated code) ----
  if (!LAST) {
#pragma unroll
    for (int ps = 0; ps < 7; ++ps) {
      int idx = ps * 512 + tid;        // 16B-chunk index, 66*48 total
      if (idx < 66 * 48) {
        int rl = idx / 48, cp = idx - rl * 48;
        int gc = cp >> 3, ch = cp & 7;
        int t = t0 - 1 + rl;
        uint4 o = make_uint4(0, 0, 0, 0);
        if (t >= 0 && t < T_) {
          const float* src = enc + ((size_t)b * T_ + t) * C_ + gc * 64 + ch * 8;
          float4 u = *(const float4*)src;
          float4 v = *(const float4*)(src + 4);
          float m = mask[b * T_ + t];
          o = make_uint4(pack2(u.x * m, u.y * m), pack2(u.z * m, u.w * m),
                         pack2(v.x * m, v.y * m), pack2(v.z * m, v.w * m));
        }
        *(uint4*)(ldsX + rl * 768 + gc * 128 + ((ch ^ (rl & 7)) << 4)) = o;
      }
    }
  } else {
#pragma unroll
    for (int ps = 0; ps < 7; ++ps) {
      int idx = ps * 512 + tid;
      if (idx < 66 * 48) {
        int rl = idx / 48, cp = idx - rl * 48;
        int gc = cp >> 3, ch = cp & 7;
        uint4 v = *(const uint4*)(x1p + ((size_t)(b * PT + t0 + rl)) * C_ +
                                  gc * 64 + ch * 8);
        *(uint4*)(ldsX + rl * 768 + gc * 128 + ((ch ^ (rl & 7)) << 4)) = v;
      }
    }
  }

  f32x4 acc[3][4];
#pragma unroll
  for (int fn = 0; fn < 3; ++fn)
#pragma unroll
    for (int fm = 0; fm < 4; ++fm) acc[fn][fm] = (f32x4){0.f, 0.f, 0.f, 0.f};

  // Stage W K-step s (48 KB = 6 x 8KB passes), 16B/lane, linear LDS dest,
  // chunk-XOR swizzle via pre-swizzled global source (rule 21).
  auto STAGE_W = [&](int buf, int s) {
    const int kk = s / 6, c0 = (s % 6) * 64;
    char* dst = ldsW[buf];
#pragma unroll
    for (int i = 0; i < 6; ++i) {
      int lin = i * 8192 + tid * 16;
      int row = lin >> 7, ch = ((lin >> 4) & 7) ^ (row & 7);
      gload16(wt + (size_t)row * KTOT + kk * C_ + c0 + ch * 8,
              dst + i * 8192 + (wid << 10));
    }
  };

  STAGE_W(0, 0);
  asm volatile("s_waitcnt vmcnt(0) lgkmcnt(0)" ::: "memory");
  __builtin_amdgcn_s_barrier();        // W step0 + X all ready
  __builtin_amdgcn_sched_barrier(0);

  int cur = 0;
#pragma unroll 1
  for (int s = 0; s < 18; ++s) {
    if (s < 17) {
      STAGE_W(cur ^ 1, s + 1);         // 6 new loads join the queue
      asm volatile("s_waitcnt vmcnt(6)" ::: "memory");  // old 6 done, new fly
    } else {
      asm volatile("s_waitcnt vmcnt(0)" ::: "memory");
    }
    __builtin_amdgcn_s_barrier();      // all waves' current buffer complete
    __builtin_amdgcn_sched_barrier(0);

    const char* W = ldsW[cur];
    const int kk = s / 6, c128 = (s % 6) * 128;
#pragma unroll
    for (int ks = 0; ks < 2; ++ks) {
      bf16x8 af[3], bx[4];
#pragma unroll
      for (int fn = 0; fn < 3; ++fn) {
        int rr = wid * 48 + fn * 16 + r16;
        af[fn] = *(const bf16x8*)(W + rr * 128 + (((ks * 4 + q) ^ (rr & 7)) << 4));
      }
#pragma unroll
      for (int fm = 0; fm < 4; ++fm) {
        int rl = fm * 16 + r16 + kk;
        bx[fm] = *(const bf16x8*)(ldsX + rl * 768 + c128 +
                                  (((ks * 4 + q) ^ (rl & 7)) << 4));
      }
#pragma unroll
      for (int fn = 0; fn < 3; ++fn)
#pragma unroll
        for (int fm = 0; fm < 4; ++fm)
          acc[fn][fm] = __builtin_amdgcn_mfma_f32_16x16x32_bf16(
              af[fn], bx[fm], acc[fn][fm], 0, 0, 0);
    }
    asm volatile("" ::: "memory");
    __builtin_amdgcn_s_barrier();      // readers done -> next overwrite safe
    __builtin_amdgcn_sched_barrier(0);
    cur ^= 1;
  }

  // --- epilogue: bias + ReLU ---
#pragma unroll
  for (int fn = 0; fn < 3; ++fn) {
    const int nb = wid * 48 + fn * 16 + q * 4;
    float b0 = bias[nb], b1 = bias[nb + 1], b2 = bias[nb + 2], b3 = bias[nb + 3];
#pragma unroll
    for (int fm = 0; fm < 4; ++fm) {
      acc[fn][fm][0] = fmaxf(acc[fn][fm][0] + b0, 0.f);
      acc[fn][fm][1] = fmaxf(acc[fn][fm][1] + b1, 0.f);
      acc[fn][fm][2] = fmaxf(acc[fn][fm][2] + b2, 0.f);
      acc[fn][fm][3] = fmaxf(acc[fn][fm][3] + b3, 0.f);
    }
  }

  // --- LN stats ---
#pragma unroll
  for (int fm = 0; fm < 4; ++fm) {
    float s = 0.f, s2 = 0.f;
#pragma unroll
    for (int fn = 0; fn < 3; ++fn)
#pragma unroll
      for (int j = 0; j < 4; ++j) {
        float v = acc[fn][fm][j];
        s += v; s2 += v * v;
      }
    s += __shfl_xor(s, 16); s += __shfl_xor(s, 32);
    s2 += __shfl_xor(s2, 16); s2 += __shfl_xor(s2, 32);
    if (l < 16) { red[wid][fm * 16 + r16][0] = s; red[wid][fm * 16 + r16][1] = s2; }
  }
  __syncthreads();
  if (tid < 64) {
    float S = 0.f, S2 = 0.f;
#pragma unroll
    for (int w = 0; w < 8; ++w) { S += red[w][tid][0]; S2 += red[w][tid][1]; }
    float mu = S / F_;
    stats[tid][0] = mu;
    stats[tid][1] = rsqrtf(S2 / F_ - mu * mu + 1e-5f);
  }
  __syncthreads();

  if (!LAST) {
#pragma unroll
    for (int fn = 0; fn < 3; ++fn) {
      const int nb = wid * 48 + fn * 16 + q * 4;
      float g0 = g[nb], g1 = g[nb + 1], g2 = g[nb + 2], g3 = g[nb + 3];
      float e0 = be[nb], e1 = be[nb + 1], e2 = be[nb + 2], e3 = be[nb + 3];
#pragma unroll
      for (int fm = 0; fm < 4; ++fm) {
        const int m = fm * 16 + r16;
        const float mu = stats[m][0], rs = stats[m][1];
        uint32_t p0 = pack2((acc[fn][fm][0] - mu) * rs * g0 + e0,
                            (acc[fn][fm][1] - mu) * rs * g1 + e1);
        uint32_t p1 = pack2((acc[fn][fm][2] - mu) * rs * g2 + e2,
                            (acc[fn][fm][3] - mu) * rs * g3 + e3);
        *(uint2*)(xout + ((size_t)(b * PT + 1 + t0 + m)) * C_ + nb) =
            make_uint2(p0, p1);
      }
    }
  } else {
    float p[4] = {0.f, 0.f, 0.f, 0.f};
#pragma unroll
    for (int fn = 0; fn < 3; ++fn) {
      const int nb = wid * 48 + fn * 16 + q * 4;
      float g0 = g[nb], g1 = g[nb + 1], g2 = g[nb + 2], g3 = g[nb + 3];
      float e0 = be[nb], e1 = be[nb + 1], e2 = be[nb + 2], e3 = be[nb + 3];
      float l0 = wl[nb], l1 = wl[nb + 1], l2 = wl[nb + 2], l3 = wl[nb + 3];
#pragma unroll
      for (int fm = 0; fm < 4; ++fm) {
        const int m = fm * 16 + r16;
        const float mu = stats[m][0], rs = stats[m][1];
        p[fm] += ((acc[fn][fm][0] - mu) * rs * g0 + e0) * l0 +
                 ((acc[fn][fm][1] - mu) * rs * g1 + e1) * l1 +
                 ((acc[fn][fm][2] - mu) * rs * g2 + e2) * l2 +
                 ((acc[fn][fm][3] - mu) * rs * g3 + e3) * l3;
      }
    }
    __syncthreads();  // red reuse
#pragma unroll
    for (int fm = 0; fm < 4; ++fm) {
      float s = p[fm];
      s += __shfl_xor(s, 16); s += __shfl_xor(s, 32);
      if (l < 16) red[wid][fm * 16 + r16][0] = s;
    }
    __syncthreads();
    if (tid < 64) {
      float S = 0.f;
#pragma unroll
      for (int w = 0; w < 8; ++w) S += red[w][tid][0];
      int t = t0 + tid;
      dpo[b * T_ + t] = (S + bl[0]) * mask[b * T_ + t];
    }
  }
}

// ---------------------------------------------------------------------------
__global__ __launch_bounds__(256) void expand_kernel(
    const float* __restrict__ enc,  // [B,T,C] f32
    const int* __restrict__ cs,     // [B,T]
    float* __restrict__ out,        // [B,M,C]
    float* __restrict__ dec) {      // [B,M] (as float)
  __shared__ int scs[T_];
  const int blk = blockIdx.x;  // B * (M/4) blocks
  const int b = blk / (M_ / 4);
  const int p0 = (blk - b * (M_ / 4)) * 4;
  for (int i = threadIdx.x; i < T_; i += 256) scs[i] = cs[b * T_ + i];
  __syncthreads();

  const int lane = threadIdx.x & 63;
  const int wid = threadIdx.x >> 6;
  const int pos = p0 + wid;
  const int total = scs[T_ - 1];
  const bool valid = pos < total;

  int idx = 0;
#pragma unroll
  for (int step = 512; step; step >>= 1)
    if (idx + step <= T_ && scs[idx + step - 1] <= pos) idx += step;
  int src = idx < T_ ? idx : T_ - 1;

  const float4* srow = (const float4*)(enc + ((size_t)b * T_ + src) * C_);
  float4* orow = (float4*)(out + ((size_t)b * M_ + pos) * C_);
  const float4 zero = make_float4(0.f, 0.f, 0.f, 0.f);
#pragma unroll
  for (int j = 0; j < 2; ++j) {
    int c4 = j * 64 + lane;
    if (c4 < C_ / 4) orow[c4] = valid ? srow[c4] : zero;
  }
  if (lane == 0) dec[b * M_ + pos] = valid ? (float)(pos + 1) : 0.f;
}

// ---------------------------------------------------------------------------
extern "C" void kernel_launch(void* const* d_in, const int* in_sizes, int n_in,
                              void* d_out, int out_size, void* d_ws,
                              size_t ws_size, hipStream_t stream) {
  const float* enc    = (const float*)d_in[0];
  const float* mask   = (const float*)d_in[1];
  const int*   target = (const int*)d_in[2];
  const float* w1    = (const float*)d_in[4];
  const float* b1    = (const float*)d_in[5];
  const float* g1    = (const float*)d_in[6];
  const float* beta1 = (const float*)d_in[7];
  const float* w2    = (const float*)d_in[8];
  const float* b2    = (const float*)d_in[9];
  const float* g2    = (const float*)d_in[10];
  const float* beta2 = (const float*)d_in[11];
  const float* wl    = (const float*)d_in[12];
  const float* bl    = (const float*)d_in[13];

  // Workspace (bf16): x1p (padded) | wt1 | wt2 | cs (i32). xm is GONE.
  ushort_t* x1p = (ushort_t*)d_ws;                    // [B][PT][C]
  ushort_t* wt1 = x1p + (size_t)B_ * PT * C_;         // [F][KTOT]
  ushort_t* wt2 = wt1 + (size_t)F_ * KTOT;
  int*      cs  = (int*)(wt2 + (size_t)F_ * KTOT);    // [B][T]

  float* out0 = (float*)d_out;                        // [B,M,C]
  float* dec  = out0 + (size_t)B_ * M_ * C_;          // [B,M]
  float* dpo  = dec + (size_t)B_ * M_;                // [B,T]

  prep_kernel<<<NWB + 48 + 8, 256, 0, stream>>>(
      target, w1, w2, x1p, wt1, wt2, cs);

  gemm_ln_kernel<false><<<B_ * (T_ / 64), 512, 0, stream>>>(
      enc, mask, nullptr, wt1, b1, g1, beta1, nullptr, nullptr, x1p, nullptr);
  gemm_ln_kernel<true><<<B_ * (T_ / 64), 512, 0, stream>>>(
      nullptr, mask, x1p, wt2, b2, g2, beta2, wl, bl, nullptr, dpo);

  expand_kernel<<<(B_ * M_) / 4, 256, 0, stream>>>(enc, cs, out0, dec);
}

// Round 11
// 80.930 us; speedup vs baseline: 4.1331x; 1.2256x over previous
//
#include <hip/hip_runtime.h>
#include <hip/hip_bf16.h>
#include <stdint.h>

// Problem constants: B=32, T=512, C=F=384, M=2048.
#define B_ 32
#define T_ 512
#define C_ 384
#define F_ 384
#define M_ 2048
#define PT (T_ + 2)      // padded time rows per batch (halo for K=3 conv)
#define KTOT (3 * C_)    // GEMM K = 1152

typedef __bf16 bf16x8 __attribute__((ext_vector_type(8)));
typedef float  f32x4  __attribute__((ext_vector_type(4)));
typedef unsigned short ushort_t;

__device__ __forceinline__ ushort_t f2bf(float f) {
  __hip_bfloat16 h = __float2bfloat16(f);
  return *reinterpret_cast<ushort_t*>(&h);
}
__device__ __forceinline__ uint32_t pack2(float a, float b) {
  return (uint32_t)f2bf(a) | ((uint32_t)f2bf(b) << 16);
}

// ---------------------------------------------------------------------------
// prep: W -> wt_perm (per-(step,wave,fragment,lane) consumption order, so the
// gemm's A-operand loads are fully-coalesced 1KB global_load_dwordx4 straight
// into registers) | x1p halo zeros | cumsum.
#define NWB 3456   // = 2*F*KTOT/256
__global__ __launch_bounds__(256) void prep_kernel(
    const int* __restrict__ target,
    const float* __restrict__ w1, const float* __restrict__ w2,
    ushort_t* __restrict__ x1p,
    ushort_t* __restrict__ wt1, ushort_t* __restrict__ wt2,
    int* __restrict__ cs) {
  const int gid = blockIdx.x;
  const int tid = threadIdx.x;
  if (gid < NWB) {
    int idx = gid * 256 + tid;          // 0 .. 2*F*KTOT
    int w = idx >= F_ * KTOT;
    int o = idx - (w ? F_ * KTOT : 0);
    int n = o / KTOT, k = o - n * KTOT;
    int kk = k / C_, c = k - kk * C_;
    // consumption coords: step s, wave wid, fragment (fn,ks), lane q*16+r16, e
    int s = kk * 6 + (c >> 6);
    int c64 = c & 63;
    int ks = c64 >> 5, qq = (c64 >> 3) & 3, e = c64 & 7;
    int wv = n / 48, rn = n - wv * 48, fn = rn >> 4, r16 = rn & 15;
    int lane = qq * 16 + r16;
    size_t dst = ((((size_t)s * 8 + wv) * 6 + fn * 2 + ks) << 9) + lane * 8 + e;
    const float* src = w ? w2 : w1;
    (w ? wt2 : wt1)[dst] = f2bf(src[(n * C_ + c) * 3 + kk]);
  } else if (gid < NWB + 48) {
    int idx = (gid - NWB) * 256 + tid;  // 0 .. B*C
    int bb = idx / C_, c = idx - bb * C_;
    x1p[(size_t)(bb * PT) * C_ + c] = 0;
    x1p[(size_t)(bb * PT + T_ + 1) * C_ + c] = 0;
  } else {
    int b = (gid - NWB - 48) * 4 + (tid >> 6);
    int lane = tid & 63;
    int base = b * T_ + lane * 8;
    int v[8];
#pragma unroll
    for (int i = 0; i < 8; ++i) v[i] = target[base + i];
#pragma unroll
    for (int i = 1; i < 8; ++i) v[i] += v[i - 1];
    int tot = v[7];
    int inc = tot;
#pragma unroll
    for (int d = 1; d < 64; d <<= 1) {
      int t = __shfl_up(inc, d);
      if (lane >= d) inc += t;
    }
    int excl = inc - tot;
#pragma unroll
    for (int i = 0; i < 8; ++i) cs[base + i] = v[i] + excl;
  }
}

// ---------------------------------------------------------------------------
// Conv-GEMM + bias + ReLU + LN (+ final linear for LAST).
// W: streamed L2 -> registers via wt_perm (coalesced 1KB/inst; W never touches
//    LDS -- it has zero cross-wave reuse). Prefetched 1 step ahead, unroll-2.
// X: ([66][384] bf16, chunk-XOR swizzled) staged ONCE per block.
// K-loop has NO barriers (only the X-stage barrier before it).
// 8 waves, wave owns 48n x 64m. Grid = 256 = 1 block/CU, 2 waves/SIMD.
template <bool LAST>
__global__ __launch_bounds__(512, 1) void gemm_ln_kernel(
    const float* __restrict__ enc,     // [B,T,C] f32      (LAST=false)
    const float* __restrict__ mask,    // [B*T]
    const ushort_t* __restrict__ x1p,  // [B][PT][C] bf16  (LAST=true in)
    const ushort_t* __restrict__ wt,   // wt_perm [18][8][6][512] bf16
    const float* __restrict__ bias, const float* __restrict__ g,
    const float* __restrict__ be,
    const float* __restrict__ wl, const float* __restrict__ bl,
    ushort_t* __restrict__ xout,       // [B][PT][C] (LAST=false out)
    float* __restrict__ dpo) {         // [B*T]      (LAST=true out)
  __shared__ char ldsX[66 * 768];      // 49.5 KB X, swizzled
  __shared__ float red[8][64][2];
  __shared__ float stats[64][2];

  const int tid = threadIdx.x;
  const int l = tid & 63, q = l >> 4, r16 = l & 15;
  const int wid = tid >> 6;            // 0..7
  const int b = blockIdx.x >> 3, t0 = (blockIdx.x & 7) * 64;

  // ---- stage X once (reg path, swizzled ds_write; R9/R10-validated) ----
  if (!LAST) {
#pragma unroll
    for (int ps = 0; ps < 7; ++ps) {
      int idx = ps * 512 + tid;        // 16B-chunk index, 66*48 total
      if (idx < 66 * 48) {
        int rl = idx / 48, cp = idx - rl * 48;
        int gc = cp >> 3, ch = cp & 7;
        int t = t0 - 1 + rl;
        uint4 o = make_uint4(0, 0, 0, 0);
        if (t >= 0 && t < T_) {
          const float* src = enc + ((size_t)b * T_ + t) * C_ + gc * 64 + ch * 8;
          float4 u = *(const float4*)src;
          float4 v = *(const float4*)(src + 4);
          float m = mask[b * T_ + t];
          o = make_uint4(pack2(u.x * m, u.y * m), pack2(u.z * m, u.w * m),
                         pack2(v.x * m, v.y * m), pack2(v.z * m, v.w * m));
        }
        *(uint4*)(ldsX + rl * 768 + gc * 128 + ((ch ^ (rl & 7)) << 4)) = o;
      }
    }
  } else {
#pragma unroll
    for (int ps = 0; ps < 7; ++ps) {
      int idx = ps * 512 + tid;
      if (idx < 66 * 48) {
        int rl = idx / 48, cp = idx - rl * 48;
        int gc = cp >> 3, ch = cp & 7;
        uint4 v = *(const uint4*)(x1p + ((size_t)(b * PT + t0 + rl)) * C_ +
                                  gc * 64 + ch * 8);
        *(uint4*)(ldsX + rl * 768 + gc * 128 + ((ch ^ (rl & 7)) << 4)) = v;
      }
    }
  }

  f32x4 acc[3][4];
#pragma unroll
  for (int fn = 0; fn < 3; ++fn)
#pragma unroll
    for (int fm = 0; fm < 4; ++fm) acc[fn][fm] = (f32x4){0.f, 0.f, 0.f, 0.f};

  // W fragment loads for step s: 6 x 1KB coalesced (lane*16B contiguous).
  const ushort_t* wlane = wt + ((size_t)wid * 6 << 9) + (l << 3);
  auto LOADW = [&](bf16x8 (&dst)[3][2], int s) {
    const ushort_t* p = wlane + (((size_t)s * 8 * 6) << 9);
#pragma unroll
    for (int fn = 0; fn < 3; ++fn)
#pragma unroll
      for (int ks = 0; ks < 2; ++ks)
        dst[fn][ks] = *(const bf16x8*)(p + ((fn * 2 + ks) << 9));
  };
  // compute step s: 8 bx ds_reads + 24 MFMA (af from registers)
  auto COMP = [&](bf16x8 (&af)[3][2], int s) {
    const int kk = s / 6, c128 = (s % 6) * 128;
#pragma unroll
    for (int ks = 0; ks < 2; ++ks) {
      bf16x8 bx[4];
#pragma unroll
      for (int fm = 0; fm < 4; ++fm) {
        int rl = fm * 16 + r16 + kk;
        bx[fm] = *(const bf16x8*)(ldsX + rl * 768 + c128 +
                                  (((ks * 4 + q) ^ (rl & 7)) << 4));
      }
#pragma unroll
      for (int fn = 0; fn < 3; ++fn)
#pragma unroll
        for (int fm = 0; fm < 4; ++fm)
          acc[fn][fm] = __builtin_amdgcn_mfma_f32_16x16x32_bf16(
              af[fn][ks], bx[fm], acc[fn][fm], 0, 0, 0);
    }
  };

  bf16x8 afA[3][2], afB[3][2];
  LOADW(afA, 0);
  __syncthreads();  // X staged (the ONLY barrier before the epilogue)
#pragma unroll 1
  for (int s = 0; s < 18; s += 2) {
    LOADW(afB, s + 1);
    COMP(afA, s);
    if (s + 2 < 18) LOADW(afA, s + 2);
    COMP(afB, s + 1);
  }

  // --- epilogue: bias + ReLU ---
#pragma unroll
  for (int fn = 0; fn < 3; ++fn) {
    const int nb = wid * 48 + fn * 16 + q * 4;
    float b0 = bias[nb], b1 = bias[nb + 1], b2 = bias[nb + 2], b3 = bias[nb + 3];
#pragma unroll
    for (int fm = 0; fm < 4; ++fm) {
      acc[fn][fm][0] = fmaxf(acc[fn][fm][0] + b0, 0.f);
      acc[fn][fm][1] = fmaxf(acc[fn][fm][1] + b1, 0.f);
      acc[fn][fm][2] = fmaxf(acc[fn][fm][2] + b2, 0.f);
      acc[fn][fm][3] = fmaxf(acc[fn][fm][3] + b3, 0.f);
    }
  }

  // --- LN stats ---
#pragma unroll
  for (int fm = 0; fm < 4; ++fm) {
    float s = 0.f, s2 = 0.f;
#pragma unroll
    for (int fn = 0; fn < 3; ++fn)
#pragma unroll
      for (int j = 0; j < 4; ++j) {
        float v = acc[fn][fm][j];
        s += v; s2 += v * v;
      }
    s += __shfl_xor(s, 16); s += __shfl_xor(s, 32);
    s2 += __shfl_xor(s2, 16); s2 += __shfl_xor(s2, 32);
    if (l < 16) { red[wid][fm * 16 + r16][0] = s; red[wid][fm * 16 + r16][1] = s2; }
  }
  __syncthreads();
  if (tid < 64) {
    float S = 0.f, S2 = 0.f;
#pragma unroll
    for (int w = 0; w < 8; ++w) { S += red[w][tid][0]; S2 += red[w][tid][1]; }
    float mu = S / F_;
    stats[tid][0] = mu;
    stats[tid][1] = rsqrtf(S2 / F_ - mu * mu + 1e-5f);
  }
  __syncthreads();

  if (!LAST) {
#pragma unroll
    for (int fn = 0; fn < 3; ++fn) {
      const int nb = wid * 48 + fn * 16 + q * 4;
      float g0 = g[nb], g1 = g[nb + 1], g2 = g[nb + 2], g3 = g[nb + 3];
      float e0 = be[nb], e1 = be[nb + 1], e2 = be[nb + 2], e3 = be[nb + 3];
#pragma unroll
      for (int fm = 0; fm < 4; ++fm) {
        const int m = fm * 16 + r16;
        const float mu = stats[m][0], rs = stats[m][1];
        uint32_t p0 = pack2((acc[fn][fm][0] - mu) * rs * g0 + e0,
                            (acc[fn][fm][1] - mu) * rs * g1 + e1);
        uint32_t p1 = pack2((acc[fn][fm][2] - mu) * rs * g2 + e2,
                            (acc[fn][fm][3] - mu) * rs * g3 + e3);
        *(uint2*)(xout + ((size_t)(b * PT + 1 + t0 + m)) * C_ + nb) =
            make_uint2(p0, p1);
      }
    }
  } else {
    float p[4] = {0.f, 0.f, 0.f, 0.f};
#pragma unroll
    for (int fn = 0; fn < 3; ++fn) {
      const int nb = wid * 48 + fn * 16 + q * 4;
      float g0 = g[nb], g1 = g[nb + 1], g2 = g[nb + 2], g3 = g[nb + 3];
      float e0 = be[nb], e1 = be[nb + 1], e2 = be[nb + 2], e3 = be[nb + 3];
      float l0 = wl[nb], l1 = wl[nb + 1], l2 = wl[nb + 2], l3 = wl[nb + 3];
#pragma unroll
      for (int fm = 0; fm < 4; ++fm) {
        const int m = fm * 16 + r16;
        const float mu = stats[m][0], rs = stats[m][1];
        p[fm] += ((acc[fn][fm][0] - mu) * rs * g0 + e0) * l0 +
                 ((acc[fn][fm][1] - mu) * rs * g1 + e1) * l1 +
                 ((acc[fn][fm][2] - mu) * rs * g2 + e2) * l2 +
                 ((acc[fn][fm][3] - mu) * rs * g3 + e3) * l3;
      }
    }
    __syncthreads();  // red reuse
#pragma unroll
    for (int fm = 0; fm < 4; ++fm) {
      float s = p[fm];
      s += __shfl_xor(s, 16); s += __shfl_xor(s, 32);
      if (l < 16) red[wid][fm * 16 + r16][0] = s;
    }
    __syncthreads();
    if (tid < 64) {
      float S = 0.f;
#pragma unroll
      for (int w = 0; w < 8; ++w) S += red[w][tid][0];
      int t = t0 + tid;
      dpo[b * T_ + t] = (S + bl[0]) * mask[b * T_ + t];
    }
  }
}

// ---------------------------------------------------------------------------
__global__ __launch_bounds__(256) void expand_kernel(
    const float* __restrict__ enc,  // [B,T,C] f32
    const int* __restrict__ cs,     // [B,T]
    float* __restrict__ out,        // [B,M,C]
    float* __restrict__ dec) {      // [B,M] (as float)
  __shared__ int scs[T_];
  const int blk = blockIdx.x;  // B * (M/4) blocks
  const int b = blk / (M_ / 4);
  const int p0 = (blk - b * (M_ / 4)) * 4;
  for (int i = threadIdx.x; i < T_; i += 256) scs[i] = cs[b * T_ + i];
  __syncthreads();

  const int lane = threadIdx.x & 63;
  const int wid = threadIdx.x >> 6;
  const int pos = p0 + wid;
  const int total = scs[T_ - 1];
  const bool valid = pos < total;

  int idx = 0;
#pragma unroll
  for (int step = 512; step; step >>= 1)
    if (idx + step <= T_ && scs[idx + step - 1] <= pos) idx += step;
  int src = idx < T_ ? idx : T_ - 1;

  const float4* srow = (const float4*)(enc + ((size_t)b * T_ + src) * C_);
  float4* orow = (float4*)(out + ((size_t)b * M_ + pos) * C_);
  const float4 zero = make_float4(0.f, 0.f, 0.f, 0.f);
#pragma unroll
  for (int j = 0; j < 2; ++j) {
    int c4 = j * 64 + lane;
    if (c4 < C_ / 4) orow[c4] = valid ? srow[c4] : zero;
  }
  if (lane == 0) dec[b * M_ + pos] = valid ? (float)(pos + 1) : 0.f;
}

// ---------------------------------------------------------------------------
extern "C" void kernel_launch(void* const* d_in, const int* in_sizes, int n_in,
                              void* d_out, int out_size, void* d_ws,
                              size_t ws_size, hipStream_t stream) {
  const float* enc    = (const float*)d_in[0];
  const float* mask   = (const float*)d_in[1];
  const int*   target = (const int*)d_in[2];
  const float* w1    = (const float*)d_in[4];
  const float* b1    = (const float*)d_in[5];
  const float* g1    = (const float*)d_in[6];
  const float* beta1 = (const float*)d_in[7];
  const float* w2    = (const float*)d_in[8];
  const float* b2    = (const float*)d_in[9];
  const float* g2    = (const float*)d_in[10];
  const float* beta2 = (const float*)d_in[11];
  const float* wl    = (const float*)d_in[12];
  const float* bl    = (const float*)d_in[13];

  // Workspace (bf16): x1p (padded) | wt1 | wt2 (permuted) | cs (i32)
  ushort_t* x1p = (ushort_t*)d_ws;                    // [B][PT][C]
  ushort_t* wt1 = x1p + (size_t)B_ * PT * C_;         // [18][8][6][512]
  ushort_t* wt2 = wt1 + (size_t)F_ * KTOT;
  int*      cs  = (int*)(wt2 + (size_t)F_ * KTOT);    // [B][T]

  float* out0 = (float*)d_out;                        // [B,M,C]
  float* dec  = out0 + (size_t)B_ * M_ * C_;          // [B,M]
  float* dpo  = dec + (size_t)B_ * M_;                // [B,T]

  prep_kernel<<<NWB + 48 + 8, 256, 0, stream>>>(
      target, w1, w2, x1p, wt1, wt2, cs);

  gemm_ln_kernel<false><<<B_ * (T_ / 64), 512, 0, stream>>>(
      enc, mask, nullptr, wt1, b1, g1, beta1, nullptr, nullptr, x1p, nullptr);
  gemm_ln_kernel<true><<<B_ * (T_ / 64), 512, 0, stream>>>(
      nullptr, mask, x1p, wt2, b2, g2, beta2, wl, bl, nullptr, dpo);

  expand_kernel<<<(B_ * M_) / 4, 256, 0, stream>>>(enc, cs, out0, dec);
}